// Round 19
// baseline (170.341 us; speedup 1.0000x reference)
//
#include <hip/hip_runtime.h>

typedef __attribute__((ext_vector_type(8))) short short8;
typedef __attribute__((ext_vector_type(4))) float f32x4;
typedef __attribute__((ext_vector_type(2))) unsigned int u32x2;
typedef unsigned short u16;
typedef unsigned int u32;

#define MFMA16 __builtin_amdgcn_mfma_f32_16x16x32_bf16

constexpr int NCH = 16;               // j-chunks per k_agg dispatch
constexpr int NJT = 8192 / 64 / NCH;  // 8 j-tiles per block

// compiler-level ordering fence for LDS a-strip (emits no instructions)
__device__ __forceinline__ void lds_order_fence() { asm volatile("" ::: "memory"); }

// async global->LDS: 16B per lane, dest = wave-uniform lds base + lane*16
__device__ __forceinline__ void gload_lds16(const void* g, void* l) {
    __builtin_amdgcn_global_load_lds((const __attribute__((address_space(1))) void*)g,
                                     (__attribute__((address_space(3))) void*)l, 16, 0, 0);
}

__device__ __forceinline__ u16 f2bf(float f) {
    u32 u = __builtin_bit_cast(u32, f);
    return (u16)((u + 0x7FFFu + ((u >> 16) & 1u)) >> 16);
}

// truncation split: f ~= hi + lo with ~16-bit combined mantissa (2^-16 rel)
__device__ __forceinline__ void split2(float f, u16& hi, u16& lo) {
    u32 u = __builtin_bit_cast(u32, f);
    hi = (u16)(u >> 16);
    float hf = __builtin_bit_cast(float, u & 0xFFFF0000u);
    float r = f - hf;  // exact (Sterbenz)
    lo = (u16)(__builtin_bit_cast(u32, r) >> 16);
}

// swizzle for [rows][32 bf16 = 64B] tiles, 4x16B slots/row: 2-way (free) on frag reads
__device__ __forceinline__ int swzA(int row, int slot) {
    return row * 64 + ((slot ^ ((row >> 1) & 3)) << 4);
}

// ---------------- merged weight transpose+split: w[K][N] -> wt{hi,lo}[N][K] ----------------
__global__ void __launch_bounds__(256) k_trs_all(const float* __restrict__ w1, u16* __restrict__ wt1h,
                                                 u16* __restrict__ wt1l,
                                                 const float* __restrict__ w2, u16* __restrict__ wt2h,
                                                 u16* __restrict__ wt2l,
                                                 const float* __restrict__ w3, u16* __restrict__ wt3h,
                                                 u16* __restrict__ wt3l) {
    const int idx = blockIdx.x * 256 + threadIdx.x;
    float v;
    int off;
    u16 *ph, *pl;
    if (idx < 131072) {  // w1: 512x256
        const int k = idx >> 8, n = idx & 255;
        v = w1[idx];
        off = n * 512 + k;
        ph = wt1h; pl = wt1l;
    } else if (idx < 196608) {  // w2: 256x256
        const int i2 = idx - 131072;
        const int k = i2 >> 8, n = i2 & 255;
        v = w2[i2];
        off = n * 256 + k;
        ph = wt2h; pl = wt2l;
    } else {  // w3: 256x32
        const int i3 = idx - 196608;
        const int k = i3 >> 5, n = i3 & 31;
        v = w3[i3];
        off = n * 256 + k;
        ph = wt3h; pl = wt3l;
    }
    u16 hh, ll;
    split2(v, hh, ll);
    ph[off] = hh;
    pl[off] = ll;
}

// ---------------- split-bf16 MFMA GEMM (BM=64) with global_load_lds staging ----------------
// LDS layout stays swzA-swizzled: the gload path pre-swizzles the GLOBAL source address
// (LDS byte tid*16 <-> row=tid>>2, slot=(tid&3)^((row>>1)&3)) so read-side swzA is unchanged.
template <int K, int BN, bool RELU, bool AF32, bool OUTSPLIT>
__global__ void __launch_bounds__(256, 2) k_gemm(const float* __restrict__ Af,
                                                 const u16* __restrict__ Ahi,
                                                 const u16* __restrict__ Alo,
                                                 const u16* __restrict__ Bthi,
                                                 const u16* __restrict__ Btlo,
                                                 const float* __restrict__ bias,
                                                 float* __restrict__ Cf, u16* __restrict__ Chi,
                                                 u16* __restrict__ Clo, const int N) {
    constexpr int NT = BN / 16;
    __shared__ __align__(16) char smem[16384];
    char* const Ah = smem;
    char* const Al = smem + 4096;
    char* const Bh = smem + 8192;
    char* const Bl = smem + 12288;
    const int tid = threadIdx.x, lane = tid & 63, w = tid >> 6;
    const int frow = lane & 15, fg = lane >> 4;
    const int m0 = blockIdx.x * 64, n0 = blockIdx.y * BN;
    const int srow = tid >> 2, sc = tid & 3;
    const int swa = swzA(srow, sc);
    // pre-swizzled source addressing for global_load_lds (linear LDS dest tid*16)
    const int slot_ld = (tid & 3) ^ ((srow >> 1) & 3);
    const float* gA = AF32 ? (Af + (m0 + srow) * K + sc * 8) : nullptr;
    const u16* sAh = AF32 ? nullptr : (Ahi + (m0 + srow) * K + slot_ld * 8);
    const u16* sAl = AF32 ? nullptr : (Alo + (m0 + srow) * K + slot_ld * 8);
    const u16* sBh = Bthi + (n0 + srow) * K + slot_ld * 8;
    const u16* sBl = Btlo + (n0 + srow) * K + slot_ld * 8;
    char* const ldsAh = Ah + w * 1024;  // wave-uniform LDS bases
    char* const ldsAl = Al + w * 1024;
    char* const ldsBh = Bh + w * 1024;
    char* const ldsBl = Bl + w * 1024;

    f32x4 acc[NT];
    float bv[NT];
#pragma unroll
    for (int nt = 0; nt < NT; nt++) {
        acc[nt] = {0.f, 0.f, 0.f, 0.f};
        bv[nt] = bias[n0 + nt * 16 + frow];
    }
    const int fra = swzA(w * 16 + frow, fg);
    int frb[NT];
#pragma unroll
    for (int nt = 0; nt < NT; nt++) frb[nt] = swzA(nt * 16 + frow, fg);

    for (int k0 = 0; k0 < K; k0 += 32) {
        short8 ah8, al8;
        if constexpr (AF32) {  // f32 A: load+split in regs before the barrier (prefetch slack)
            const f32x4 a0 = *(const f32x4*)(gA + k0);
            const f32x4 a1 = *(const f32x4*)(gA + k0 + 4);
#pragma unroll
            for (int i = 0; i < 4; i++) { u16 hh, ll; split2(a0[i], hh, ll); ah8[i] = (short)hh; al8[i] = (short)ll; }
#pragma unroll
            for (int i = 0; i < 4; i++) { u16 hh, ll; split2(a1[i], hh, ll); ah8[4 + i] = (short)hh; al8[4 + i] = (short)ll; }
        }
        __syncthreads();  // previous iteration's frag reads done before overwrite
        if constexpr (AF32) {
            *(short8*)(Ah + swa) = ah8;
            *(short8*)(Al + swa) = al8;
        } else {
            gload_lds16(sAh + k0, ldsAh);
            gload_lds16(sAl + k0, ldsAl);
        }
        if (BN == 64) {  // all 4 waves cover the 64-row B tile
            gload_lds16(sBh + k0, ldsBh);
            gload_lds16(sBl + k0, ldsBl);
        } else if (w < 2) {  // BN=32: waves 0,1 cover 32 rows
            gload_lds16(sBh + k0, ldsBh);
            gload_lds16(sBl + k0, ldsBl);
        }
        __syncthreads();  // drains vmcnt(0): gload_lds data visible
        const short8 afh = *(const short8*)(Ah + fra);
        const short8 afl = *(const short8*)(Al + fra);
#pragma unroll
        for (int nt = 0; nt < NT; nt++) {
            const short8 bfh = *(const short8*)(Bh + frb[nt]);
            const short8 bfl = *(const short8*)(Bl + frb[nt]);
            acc[nt] = MFMA16(afh, bfh, acc[nt], 0, 0, 0);
            acc[nt] = MFMA16(afh, bfl, acc[nt], 0, 0, 0);
            acc[nt] = MFMA16(afl, bfh, acc[nt], 0, 0, 0);
        }
    }
#pragma unroll
    for (int nt = 0; nt < NT; nt++) {
#pragma unroll
        for (int r = 0; r < 4; r++) {
            float v = acc[nt][r] + bv[nt];
            if (RELU) v = fmaxf(v, 0.f);
            const int row = m0 + w * 16 + fg * 4 + r, col = n0 + nt * 16 + frow;
            if constexpr (OUTSPLIT) {
                u16 hh, ll;
                split2(v, hh, ll);
                Chi[row * N + col] = hh;
                Clo[row * N + col] = ll;
            } else {
                Cf[row * N + col] = v;
            }
        }
    }
}

// ---------------- post: sq, h hi/lo, B1t = (h@gw1)^T / N ----------------
__global__ void __launch_bounds__(256) k_post(const float* __restrict__ H,
                                              const float* __restrict__ gw1,
                                              u16* __restrict__ hhi, u16* __restrict__ hlo,
                                              float* __restrict__ sqv, u16* __restrict__ B1t) {
    __shared__ float gs[512];
    const int tid = threadIdx.x;
    gs[tid] = gw1[tid];
    gs[tid + 256] = gw1[tid + 256];
    __syncthreads();
    const int j = blockIdx.x * 256 + tid;
    float h[32];
#pragma unroll
    for (int q = 0; q < 8; q++) {
        f32x4 v = *(const f32x4*)(H + j * 32 + q * 4);
        h[q * 4 + 0] = v[0]; h[q * 4 + 1] = v[1]; h[q * 4 + 2] = v[2]; h[q * 4 + 3] = v[3];
    }
    float s = 0.f;
#pragma unroll
    for (int k = 0; k < 32; k++) s = fmaf(h[k], h[k], s);
    sqv[j] = s;
#pragma unroll
    for (int q = 0; q < 4; q++) {
        short8 vh, vl;
#pragma unroll
        for (int e = 0; e < 8; e++) {
            u16 hh, ll;
            split2(h[q * 8 + e], hh, ll);
            vh[e] = (short)hh; vl[e] = (short)ll;
        }
        *(short8*)(hhi + j * 32 + q * 8) = vh;
        *(short8*)(hlo + j * 32 + q * 8) = vl;
    }
    const float inv = 0.0001220703125f;  // 1/8192
#pragma unroll
    for (int f = 0; f < 16; f++) {
        float a = 0.f;
#pragma unroll
        for (int k = 0; k < 32; k++) a = fmaf(h[k], gs[k * 16 + f], a);
        B1t[f * 8192 + j] = f2bf(a * inv);
    }
}

// elementwise for one 16-src group: d2 -> d -> sigmoid -> bf16 pair-pack -> a-strip
template <bool DIAG>
__device__ __forceinline__ void ew_pack(char* astr, int awoff, const f32x4 s, const f32x4 sq4,
                                        float sq_i, float c0, float c1, int jloc, int il) {
    float p[4];
#pragma unroll
    for (int r = 0; r < 4; r++) {
        float d2 = fmaf(s[r], -2.f, sq_i + sq4[r]);
        d2 = fmaxf(d2, 0.f);
        float d = __builtin_amdgcn_sqrtf(d2);
        if (DIAG) {
            if (jloc + r == il) d = 0.f;  // exact diagonal (ref: where(d2>0,...))
        }
        const float z = fmaf(d, c1, c0);
        p[r] = __builtin_amdgcn_rcpf(1.f + __builtin_amdgcn_exp2f(z));
    }
    u32 w0, w1;
    asm("v_cvt_pk_bf16_f32 %0, %1, %2" : "=v"(w0) : "v"(p[0]), "v"(p[1]));
    asm("v_cvt_pk_bf16_f32 %0, %1, %2" : "=v"(w1) : "v"(p[2]), "v"(p[3]));
    u32x2 pk = {w0, w1};
    *(u32x2*)(astr + awoff) = pk;
}

// ---------------- fused aggregation: 8-wave blocks, double-buffer, ONE barrier/jt ----------------
// (R17-exact structure; A-fragment store uses NON-TEMPORAL writes to keep L2 clean)
template <bool STOREA>
__global__ void __launch_bounds__(512) k_agg(const u16* __restrict__ hhi, const u16* __restrict__ hlo,
                                             const float* __restrict__ sqv, const u16* __restrict__ Bt,
                                             float* __restrict__ P, u16* __restrict__ Afr,
                                             const float* __restrict__ tp, const float* __restrict__ thp) {
    // LDS = 2x4096 (hi) + 2x4096 (lo) + 8x2048 (a-strips) = 32768 B
    __shared__ __align__(16) char smem[32768];
    char* const bufh = smem;            // 2 x [64][32] bf16 hi (swizzled)
    char* const bufl = smem + 8192;     // 2 x [64][32] bf16 lo
    char* const astr0 = smem + 16384;   // 8 x [16][64] bf16 wave-private a-strips

    const int tid = threadIdx.x, lane = tid & 63, w = tid >> 6;  // w in [0,8)
    const int frow = lane & 15, fg = lane >> 4;
    const int dstbase = blockIdx.x * 128;
    const int chunk = blockIdx.y;
    const float t = tp[0], th = thp[0];
    const float c1 = -t * 1.44269504088896340736f;  // -t*log2(e)
    const float c0 = c1 * th;
    char* const astr = astr0 + w * 2048;
    const int dfi = blockIdx.x * 8 + w;  // global dst-fragment index [0,512)

    const bool stager = (tid < 256);
    const int srow = (tid & 255) >> 2, sc = tid & 3;
    const int swa = swzA(srow, sc);

    // dst (B-operand) frags + |h_i|^2, straight from global (L2-resident)
    const int igf = dstbase + w * 16 + frow;
    const short8 hdh = *(const short8*)(hhi + igf * 32 + fg * 8);
    const short8 hdl = *(const short8*)(hlo + igf * 32 + fg * 8);
    const float sq_i = sqv[igf];
    // diagonal: wave w's dst rows live in src-tile dstbase + (w>>2)*64, local row il
    const int jdiag = dstbase + ((w >> 2) << 6);
    const int il = (w & 3) * 16 + frow;

    int awo[4], ard[2];
#pragma unroll
    for (int jj = 0; jj < 4; jj++)
        awo[jj] = frow * 128 + (((2 * jj + (fg >> 1)) ^ (frow & 7)) << 4) + ((fg & 1) << 3);
#pragma unroll
    for (int h = 0; h < 2; h++) ard[h] = frow * 128 + (((4 * h + fg) ^ (frow & 7)) << 4);

    f32x4 outacc = {0.f, 0.f, 0.f, 0.f};
    const u16* bgp = Bt + frow * 8192;

    const int jt0 = chunk * NJT;
    // prologue: tile0 -> buf0 (via regs), tile1 -> regs (staging threads only)
    short8 pvh, pvl;
    if (stager) {
        pvh = *(const short8*)(hhi + ((jt0 * 64) + srow) * 32 + sc * 8);
        pvl = *(const short8*)(hlo + ((jt0 * 64) + srow) * 32 + sc * 8);
        *(short8*)(bufh + swa) = pvh;
        *(short8*)(bufl + swa) = pvl;
        if (NJT > 1) {
            const int jn = (jt0 + 1) * 64;
            pvh = *(const short8*)(hhi + (jn + srow) * 32 + sc * 8);
            pvl = *(const short8*)(hlo + (jn + srow) * 32 + sc * 8);
        }
    }

    for (int it = 0; it < NJT; ++it) {
        const int b = it & 1;
        const int jbase = (jt0 + it) * 64;
        // global loads for THIS tile, issued before the barrier so their latency hides
        // under barrier + staging + hs-reads + S'-MFMAs (fences below would otherwise pin them)
        f32x4 sqg[4];
        short8 bfg[2];
#pragma unroll
        for (int q = 0; q < 4; q++) sqg[q] = *(const f32x4*)(sqv + jbase + q * 16 + fg * 4);
#pragma unroll
        for (int q = 0; q < 2; q++) bfg[q] = *(const short8*)(bgp + jbase + q * 32 + fg * 8);
        // Single barrier: publishes tile `it` (stored last iter / prologue) AND separates
        // iter it-1's reads of buf[b^1] from this iter's write to buf[b^1].
        __syncthreads();
        if (stager) {
            if (it + 1 < NJT) {  // store tile it+1 (in regs) into the other buffer
                *(short8*)(bufh + (b ^ 1) * 4096 + swa) = pvh;
                *(short8*)(bufl + (b ^ 1) * 4096 + swa) = pvl;
            }
            if (it + 2 < NJT) {  // prefetch tile it+2 into regs
                const int jn = (jt0 + it + 2) * 64;
                pvh = *(const short8*)(hhi + (jn + srow) * 32 + sc * 8);
                pvl = *(const short8*)(hlo + (jn + srow) * 32 + sc * 8);
            }
        }
        char* const bh = bufh + b * 4096;
        char* const bl = bufl + b * 4096;
        const bool diag = (jbase == jdiag);
#pragma unroll
        for (int h = 0; h < 2; ++h) {
            const short8 hs0h = *(const short8*)(bh + swzA(h * 32 + frow, fg));
            const short8 hs0l = *(const short8*)(bl + swzA(h * 32 + frow, fg));
            const short8 hs1h = *(const short8*)(bh + swzA(h * 32 + 16 + frow, fg));
            const short8 hs1l = *(const short8*)(bl + swzA(h * 32 + 16 + frow, fg));
            // S' = Hs . Hd^T (swapped: acc->PV-A-frag transpose is a packed b64 LDS write)
            f32x4 s0 = {0.f, 0.f, 0.f, 0.f}, s1 = {0.f, 0.f, 0.f, 0.f};
            s0 = MFMA16(hs0h, hdh, s0, 0, 0, 0);
            s0 = MFMA16(hs0h, hdl, s0, 0, 0, 0);
            s0 = MFMA16(hs0l, hdh, s0, 0, 0, 0);
            s1 = MFMA16(hs1h, hdh, s1, 0, 0, 0);
            s1 = MFMA16(hs1h, hdl, s1, 0, 0, 0);
            s1 = MFMA16(hs1l, hdh, s1, 0, 0, 0);
            lds_order_fence();  // WAR: prior af read (prev h / prev jt) before these writes
            if (diag) {  // uniform branch: only 1 tile per wave-row-block has the diagonal
                ew_pack<true>(astr, awo[2 * h], s0, sqg[2 * h], sq_i, c0, c1, (2 * h) * 16 + fg * 4, il);
                ew_pack<true>(astr, awo[2 * h + 1], s1, sqg[2 * h + 1], sq_i, c0, c1, (2 * h + 1) * 16 + fg * 4, il);
            } else {
                ew_pack<false>(astr, awo[2 * h], s0, sqg[2 * h], sq_i, c0, c1, 0, -1);
                ew_pack<false>(astr, awo[2 * h + 1], s1, sqg[2 * h + 1], sq_i, c0, c1, 0, -1);
            }
            lds_order_fence();  // RAW: pack writes ordered before the af read (TBAA fix)
            // PV: out += a(16x32) @ B(32x16)
            const short8 af = *(const short8*)(astr + ard[h]);
            if (STOREA) {  // materialize A-fragment, NON-TEMPORAL: bypass L2, land in L3/HBM
                __builtin_nontemporal_store(
                    af, (short8*)(Afr + (dfi * 128 + (jt0 + it)) * 1024 + lane * 16 + h * 8));
            }
            outacc = MFMA16(af, bfg[h], outacc, 0, 0, 0);
        }
    }
#pragma unroll
    for (int r = 0; r < 4; r++) {
        const int ig = dstbase + w * 16 + fg * 4 + r;
        P[(chunk * 8192 + ig) * 16 + frow] = outacc[r];
    }
}

// ---------------- pass-2 aggregation from materialized A: pure PV ----------------
__global__ void __launch_bounds__(512) k_agg2(const u16* __restrict__ Afr, const u16* __restrict__ Bt,
                                              float* __restrict__ P) {
    const int tid = threadIdx.x, lane = tid & 63, w = tid >> 6;
    const int frow = lane & 15, fg = lane >> 4;
    const int dstbase = blockIdx.x * 128;
    const int chunk = blockIdx.y;
    const int dfi = blockIdx.x * 8 + w;
    const u16* bgp = Bt + frow * 8192;
    const int jt0 = chunk * NJT;

    f32x4 outacc = {0.f, 0.f, 0.f, 0.f};
#pragma unroll
    for (int it = 0; it < NJT; ++it) {
        const int sti = jt0 + it;
        const int jbase = sti * 64;
        const u16* ap = Afr + (dfi * 128 + sti) * 1024 + lane * 16;
        const short8 af0 = *(const short8*)(ap);
        const short8 af1 = *(const short8*)(ap + 8);
        const short8 bf0 = *(const short8*)(bgp + jbase + fg * 8);
        const short8 bf1 = *(const short8*)(bgp + jbase + 32 + fg * 8);
        outacc = MFMA16(af0, bf0, outacc, 0, 0, 0);
        outacc = MFMA16(af1, bf1, outacc, 0, 0, 0);
    }
#pragma unroll
    for (int r = 0; r < 4; r++) {
        const int ig = dstbase + w * 16 + fg * 4 + r;
        P[(chunk * 8192 + ig) * 16 + frow] = outacc[r];
    }
}

// ---------------- reduce partials -> g1 -> B2t = (g1@gw2)^T / N (rows 8..15 zero) ----------------
__global__ void __launch_bounds__(256) k_reduce1(const float* __restrict__ P,
                                                 const float* __restrict__ gw2,
                                                 const float* __restrict__ gb1,
                                                 u16* __restrict__ B2t) {
    __shared__ float gs[128];
    const int tid = threadIdx.x;
    if (tid < 128) gs[tid] = gw2[tid];
    __syncthreads();
    const int j = blockIdx.x * 256 + tid;
    float g[16];
#pragma unroll
    for (int q = 0; q < 4; q++) {
        f32x4 v = *(const f32x4*)(P + j * 16 + q * 4);
        g[q * 4 + 0] = v[0]; g[q * 4 + 1] = v[1]; g[q * 4 + 2] = v[2]; g[q * 4 + 3] = v[3];
    }
#pragma unroll
    for (int c = 1; c < NCH; c++) {
#pragma unroll
        for (int q = 0; q < 4; q++) {
            f32x4 v = *(const f32x4*)(P + (c * 8192 + j) * 16 + q * 4);
            g[q * 4 + 0] += v[0]; g[q * 4 + 1] += v[1]; g[q * 4 + 2] += v[2]; g[q * 4 + 3] += v[3];
        }
    }
#pragma unroll
    for (int f = 0; f < 16; f++) g[f] = fmaxf(g[f] + gb1[f], 0.f);
    const float inv = 0.0001220703125f;
#pragma unroll
    for (int f2 = 0; f2 < 8; f2++) {
        float a = 0.f;
#pragma unroll
        for (int k = 0; k < 16; k++) a = fmaf(g[k], gs[k * 8 + f2], a);
        B2t[f2 * 8192 + j] = f2bf(a * inv);
    }
#pragma unroll
    for (int f2 = 8; f2 < 16; f2++) B2t[f2 * 8192 + j] = 0;
}

// ---------------- final: g2 -> relu(g2@lw1+lb1) -> @lw2+lb2 ----------------
__global__ void __launch_bounds__(256) k_final(const float* __restrict__ P,
                                               const float* __restrict__ gb2,
                                               const float* __restrict__ lw1,
                                               const float* __restrict__ lb1,
                                               const float* __restrict__ lw2,
                                               const float* __restrict__ lb2,
                                               float* __restrict__ out) {
    __shared__ float s1[128], s2[256];
    const int tid = threadIdx.x;
    if (tid < 128) s1[tid] = lw1[tid];
    s2[tid] = lw2[tid];
    __syncthreads();
    const int j = blockIdx.x * 256 + tid;
    float g[8];
#pragma unroll
    for (int q = 0; q < 2; q++) {
        f32x4 v = *(const f32x4*)(P + j * 16 + q * 4);
        g[q * 4 + 0] = v[0]; g[q * 4 + 1] = v[1]; g[q * 4 + 2] = v[2]; g[q * 4 + 3] = v[3];
    }
#pragma unroll
    for (int c = 1; c < NCH; c++) {
#pragma unroll
        for (int q = 0; q < 2; q++) {
            f32x4 v = *(const f32x4*)(P + (c * 8192 + j) * 16 + q * 4);
            g[q * 4 + 0] += v[0]; g[q * 4 + 1] += v[1]; g[q * 4 + 2] += v[2]; g[q * 4 + 3] += v[3];
        }
    }
#pragma unroll
    for (int f = 0; f < 8; f++) g[f] = fmaxf(g[f] + gb2[f], 0.f);
    float l1[16];
#pragma unroll
    for (int f = 0; f < 16; f++) {
        float a = lb1[f];
#pragma unroll
        for (int k = 0; k < 8; k++) a = fmaf(g[k], s1[k * 16 + f], a);
        l1[f] = fmaxf(a, 0.f);
    }
#pragma unroll
    for (int q = 0; q < 4; q++) {
        f32x4 v;
#pragma unroll
        for (int e = 0; e < 4; e++) {
            const int f = q * 4 + e;
            float a = lb2[f];
#pragma unroll
            for (int k = 0; k < 16; k++) a = fmaf(l1[k], s2[k * 16 + f], a);
            v[e] = a;
        }
        *(f32x4*)(out + j * 16 + q * 4) = v;
    }
}

extern "C" void kernel_launch(void* const* d_in, const int* in_sizes, int n_in,
                              void* d_out, int out_size, void* d_ws, size_t ws_size,
                              hipStream_t stream) {
    (void)in_sizes; (void)n_in; (void)out_size;
    const float* x   = (const float*)d_in[0];
    const float* w1  = (const float*)d_in[1];
    const float* b1  = (const float*)d_in[2];
    const float* w2  = (const float*)d_in[3];
    const float* b2  = (const float*)d_in[4];
    const float* w3  = (const float*)d_in[5];
    const float* b3  = (const float*)d_in[6];
    const float* t   = (const float*)d_in[7];
    const float* th  = (const float*)d_in[8];
    const float* gw1 = (const float*)d_in[9];
    const float* gb1 = (const float*)d_in[10];
    const float* gw2 = (const float*)d_in[11];
    const float* gb2 = (const float*)d_in[12];
    const float* lw1 = (const float*)d_in[13];
    const float* lb1 = (const float*)d_in[14];
    const float* lw2 = (const float*)d_in[15];
    const float* lb2 = (const float*)d_in[16];

    char* ws = (char*)d_ws;
    u16* wt1h = (u16*)(ws + 0);          // [256][512] hi
    u16* wt1l = (u16*)(ws + 262144);     // [256][512] lo
    u16* wt2h = (u16*)(ws + 524288);     // [256][256] hi
    u16* wt2l = (u16*)(ws + 655360);     // [256][256] lo
    u16* wt3h = (u16*)(ws + 786432);     // [32][256] hi
    u16* wt3l = (u16*)(ws + 802816);     // [32][256] lo
    u16* H1h  = (u16*)(ws + 819200);     // [8192][256] hi (aliased by P later)
    u16* H1l  = (u16*)(ws + 5013504);    // [8192][256] lo
    float* P  = (float*)(ws + 819200);   // [16][8192][16] partials (8MB, H1 dead by then)
    u16* H2h  = (u16*)(ws + 9207808);    // [8192][256] hi
    u16* H2l  = (u16*)(ws + 13402112);   // [8192][256] lo
    float* H  = (float*)(ws + 17596416); // [8192][32] f32
    u16*   hhi = (u16*)(ws + 18644992);  // [8192][32] bf16 hi
    u16*   hlo = (u16*)(ws + 19169280);  // [8192][32] bf16 lo
    float* sqv = (float*)(ws + 19693568);// [8192]
    u16*   B1t = (u16*)(ws + 19726336);  // [16][8192] bf16
    u16*   B2t = (u16*)(ws + 19988480);  // [16][8192] bf16 (rows 8..15 zero)
    u16*   Afr = (u16*)(ws + 20971520);  // [512 dfrag][128 stile][1024] bf16 = 134.2 MB
    const bool bigws = ws_size >= (20971520ull + 134217728ull);

    k_trs_all<<<800, 256, 0, stream>>>(w1, wt1h, wt1l, w2, wt2h, wt2l, w3, wt3h, wt3l);

    k_gemm<512, 64, true, true, true><<<dim3(128, 4), 256, 0, stream>>>(
        x, nullptr, nullptr, wt1h, wt1l, b1, nullptr, H1h, H1l, 256);
    k_gemm<256, 64, true, false, true><<<dim3(128, 4), 256, 0, stream>>>(
        nullptr, H1h, H1l, wt2h, wt2l, b2, nullptr, H2h, H2l, 256);
    k_gemm<256, 32, false, false, false><<<dim3(128, 1), 256, 0, stream>>>(
        nullptr, H2h, H2l, wt3h, wt3l, b3, H, nullptr, nullptr, 32);

    k_post<<<32, 256, 0, stream>>>(H, gw1, hhi, hlo, sqv, B1t);

    if (bigws) {
        k_agg<true><<<dim3(64, NCH), 512, 0, stream>>>(hhi, hlo, sqv, B1t, P, Afr, t, th);
        k_reduce1<<<32, 256, 0, stream>>>(P, gw2, gb1, B2t);
        k_agg2<<<dim3(64, NCH), 512, 0, stream>>>(Afr, B2t, P);
    } else {
        k_agg<false><<<dim3(64, NCH), 512, 0, stream>>>(hhi, hlo, sqv, B1t, P, nullptr, t, th);
        k_reduce1<<<32, 256, 0, stream>>>(P, gw2, gb1, B2t);
        k_agg<false><<<dim3(64, NCH), 512, 0, stream>>>(hhi, hlo, sqv, B2t, P, nullptr, t, th);
    }
    k_final<<<32, 256, 0, stream>>>(P, gb2, lw1, lb1, lw2, lb2, (float*)d_out);
}

// Round 20
// 124.217 us; speedup vs baseline: 1.3713x; 1.3713x over previous
//
#include <hip/hip_runtime.h>

typedef __attribute__((ext_vector_type(8))) short short8;
typedef __attribute__((ext_vector_type(4))) float f32x4;
typedef __attribute__((ext_vector_type(2))) unsigned int u32x2;
typedef unsigned short u16;
typedef unsigned int u32;

#define MFMA16 __builtin_amdgcn_mfma_f32_16x16x32_bf16

constexpr int NCH = 16;               // j-chunks per k_agg dispatch
constexpr int NJT = 8192 / 64 / NCH;  // 8 j-tiles per block

// compiler-level ordering fence for LDS a-strip (emits no instructions)
__device__ __forceinline__ void lds_order_fence() { asm volatile("" ::: "memory"); }

// async global->LDS: 16B per lane, dest = wave-uniform lds base + lane*16
__device__ __forceinline__ void gload_lds16(const void* g, void* l) {
    __builtin_amdgcn_global_load_lds((const __attribute__((address_space(1))) void*)g,
                                     (__attribute__((address_space(3))) void*)l, 16, 0, 0);
}

__device__ __forceinline__ u16 f2bf(float f) {
    u32 u = __builtin_bit_cast(u32, f);
    return (u16)((u + 0x7FFFu + ((u >> 16) & 1u)) >> 16);
}

// truncation split: f ~= hi + lo with ~16-bit combined mantissa (2^-16 rel)
__device__ __forceinline__ void split2(float f, u16& hi, u16& lo) {
    u32 u = __builtin_bit_cast(u32, f);
    hi = (u16)(u >> 16);
    float hf = __builtin_bit_cast(float, u & 0xFFFF0000u);
    float r = f - hf;  // exact (Sterbenz)
    lo = (u16)(__builtin_bit_cast(u32, r) >> 16);
}

// swizzle for [rows][32 bf16 = 64B] tiles, 4x16B slots/row: 2-way (free) on frag reads
__device__ __forceinline__ int swzA(int row, int slot) {
    return row * 64 + ((slot ^ ((row >> 1) & 3)) << 4);
}

// ---------------- merged weight transpose+split: w[K][N] -> wt{hi,lo}[N][K] ----------------
__global__ void __launch_bounds__(256) k_trs_all(const float* __restrict__ w1, u16* __restrict__ wt1h,
                                                 u16* __restrict__ wt1l,
                                                 const float* __restrict__ w2, u16* __restrict__ wt2h,
                                                 u16* __restrict__ wt2l,
                                                 const float* __restrict__ w3, u16* __restrict__ wt3h,
                                                 u16* __restrict__ wt3l) {
    const int idx = blockIdx.x * 256 + threadIdx.x;
    float v;
    int off;
    u16 *ph, *pl;
    if (idx < 131072) {  // w1: 512x256
        const int k = idx >> 8, n = idx & 255;
        v = w1[idx];
        off = n * 512 + k;
        ph = wt1h; pl = wt1l;
    } else if (idx < 196608) {  // w2: 256x256
        const int i2 = idx - 131072;
        const int k = i2 >> 8, n = i2 & 255;
        v = w2[i2];
        off = n * 256 + k;
        ph = wt2h; pl = wt2l;
    } else {  // w3: 256x32
        const int i3 = idx - 196608;
        const int k = i3 >> 5, n = i3 & 31;
        v = w3[i3];
        off = n * 256 + k;
        ph = wt3h; pl = wt3l;
    }
    u16 hh, ll;
    split2(v, hh, ll);
    ph[off] = hh;
    pl[off] = ll;
}

// ---------------- split-bf16 MFMA GEMM (BM=64) with global_load_lds staging ----------------
// LDS layout stays swzA-swizzled: the gload path pre-swizzles the GLOBAL source address
// (LDS byte tid*16 <-> row=tid>>2, slot=(tid&3)^((row>>1)&3)) so read-side swzA is unchanged.
template <int K, int BN, bool RELU, bool AF32, bool OUTSPLIT>
__global__ void __launch_bounds__(256, 2) k_gemm(const float* __restrict__ Af,
                                                 const u16* __restrict__ Ahi,
                                                 const u16* __restrict__ Alo,
                                                 const u16* __restrict__ Bthi,
                                                 const u16* __restrict__ Btlo,
                                                 const float* __restrict__ bias,
                                                 float* __restrict__ Cf, u16* __restrict__ Chi,
                                                 u16* __restrict__ Clo, const int N) {
    constexpr int NT = BN / 16;
    __shared__ __align__(16) char smem[16384];
    char* const Ah = smem;
    char* const Al = smem + 4096;
    char* const Bh = smem + 8192;
    char* const Bl = smem + 12288;
    const int tid = threadIdx.x, lane = tid & 63, w = tid >> 6;
    const int frow = lane & 15, fg = lane >> 4;
    const int m0 = blockIdx.x * 64, n0 = blockIdx.y * BN;
    const int srow = tid >> 2, sc = tid & 3;
    const int swa = swzA(srow, sc);
    // pre-swizzled source addressing for global_load_lds (linear LDS dest tid*16)
    const int slot_ld = (tid & 3) ^ ((srow >> 1) & 3);
    const float* gA = AF32 ? (Af + (m0 + srow) * K + sc * 8) : nullptr;
    const u16* sAh = AF32 ? nullptr : (Ahi + (m0 + srow) * K + slot_ld * 8);
    const u16* sAl = AF32 ? nullptr : (Alo + (m0 + srow) * K + slot_ld * 8);
    const u16* sBh = Bthi + (n0 + srow) * K + slot_ld * 8;
    const u16* sBl = Btlo + (n0 + srow) * K + slot_ld * 8;
    char* const ldsAh = Ah + w * 1024;  // wave-uniform LDS bases
    char* const ldsAl = Al + w * 1024;
    char* const ldsBh = Bh + w * 1024;
    char* const ldsBl = Bl + w * 1024;

    f32x4 acc[NT];
    float bv[NT];
#pragma unroll
    for (int nt = 0; nt < NT; nt++) {
        acc[nt] = {0.f, 0.f, 0.f, 0.f};
        bv[nt] = bias[n0 + nt * 16 + frow];
    }
    const int fra = swzA(w * 16 + frow, fg);
    int frb[NT];
#pragma unroll
    for (int nt = 0; nt < NT; nt++) frb[nt] = swzA(nt * 16 + frow, fg);

    for (int k0 = 0; k0 < K; k0 += 32) {
        short8 ah8, al8;
        if constexpr (AF32) {  // f32 A: load+split in regs before the barrier (prefetch slack)
            const f32x4 a0 = *(const f32x4*)(gA + k0);
            const f32x4 a1 = *(const f32x4*)(gA + k0 + 4);
#pragma unroll
            for (int i = 0; i < 4; i++) { u16 hh, ll; split2(a0[i], hh, ll); ah8[i] = (short)hh; al8[i] = (short)ll; }
#pragma unroll
            for (int i = 0; i < 4; i++) { u16 hh, ll; split2(a1[i], hh, ll); ah8[4 + i] = (short)hh; al8[4 + i] = (short)ll; }
        }
        __syncthreads();  // previous iteration's frag reads done before overwrite
        if constexpr (AF32) {
            *(short8*)(Ah + swa) = ah8;
            *(short8*)(Al + swa) = al8;
        } else {
            gload_lds16(sAh + k0, ldsAh);
            gload_lds16(sAl + k0, ldsAl);
        }
        if (BN == 64) {  // all 4 waves cover the 64-row B tile
            gload_lds16(sBh + k0, ldsBh);
            gload_lds16(sBl + k0, ldsBl);
        } else if (w < 2) {  // BN=32: waves 0,1 cover 32 rows
            gload_lds16(sBh + k0, ldsBh);
            gload_lds16(sBl + k0, ldsBl);
        }
        __syncthreads();  // drains vmcnt(0): gload_lds data visible
        const short8 afh = *(const short8*)(Ah + fra);
        const short8 afl = *(const short8*)(Al + fra);
#pragma unroll
        for (int nt = 0; nt < NT; nt++) {
            const short8 bfh = *(const short8*)(Bh + frb[nt]);
            const short8 bfl = *(const short8*)(Bl + frb[nt]);
            acc[nt] = MFMA16(afh, bfh, acc[nt], 0, 0, 0);
            acc[nt] = MFMA16(afh, bfl, acc[nt], 0, 0, 0);
            acc[nt] = MFMA16(afl, bfh, acc[nt], 0, 0, 0);
        }
    }
#pragma unroll
    for (int nt = 0; nt < NT; nt++) {
#pragma unroll
        for (int r = 0; r < 4; r++) {
            float v = acc[nt][r] + bv[nt];
            if (RELU) v = fmaxf(v, 0.f);
            const int row = m0 + w * 16 + fg * 4 + r, col = n0 + nt * 16 + frow;
            if constexpr (OUTSPLIT) {
                u16 hh, ll;
                split2(v, hh, ll);
                Chi[row * N + col] = hh;
                Clo[row * N + col] = ll;
            } else {
                Cf[row * N + col] = v;
            }
        }
    }
}

// ---------------- post: sq, h hi/lo, B1t = (h@gw1)^T / N ----------------
__global__ void __launch_bounds__(256) k_post(const float* __restrict__ H,
                                              const float* __restrict__ gw1,
                                              u16* __restrict__ hhi, u16* __restrict__ hlo,
                                              float* __restrict__ sqv, u16* __restrict__ B1t) {
    __shared__ float gs[512];
    const int tid = threadIdx.x;
    gs[tid] = gw1[tid];
    gs[tid + 256] = gw1[tid + 256];
    __syncthreads();
    const int j = blockIdx.x * 256 + tid;
    float h[32];
#pragma unroll
    for (int q = 0; q < 8; q++) {
        f32x4 v = *(const f32x4*)(H + j * 32 + q * 4);
        h[q * 4 + 0] = v[0]; h[q * 4 + 1] = v[1]; h[q * 4 + 2] = v[2]; h[q * 4 + 3] = v[3];
    }
    float s = 0.f;
#pragma unroll
    for (int k = 0; k < 32; k++) s = fmaf(h[k], h[k], s);
    sqv[j] = s;
#pragma unroll
    for (int q = 0; q < 4; q++) {
        short8 vh, vl;
#pragma unroll
        for (int e = 0; e < 8; e++) {
            u16 hh, ll;
            split2(h[q * 8 + e], hh, ll);
            vh[e] = (short)hh; vl[e] = (short)ll;
        }
        *(short8*)(hhi + j * 32 + q * 8) = vh;
        *(short8*)(hlo + j * 32 + q * 8) = vl;
    }
    const float inv = 0.0001220703125f;  // 1/8192
#pragma unroll
    for (int f = 0; f < 16; f++) {
        float a = 0.f;
#pragma unroll
        for (int k = 0; k < 32; k++) a = fmaf(h[k], gs[k * 16 + f], a);
        B1t[f * 8192 + j] = f2bf(a * inv);
    }
}

// elementwise for one 16-src group: d2 -> d -> sigmoid -> bf16 pair-pack -> a-strip
template <bool DIAG>
__device__ __forceinline__ void ew_pack(char* astr, int awoff, const f32x4 s, const f32x4 sq4,
                                        float sq_i, float c0, float c1, int jloc, int il) {
    float p[4];
#pragma unroll
    for (int r = 0; r < 4; r++) {
        float d2 = fmaf(s[r], -2.f, sq_i + sq4[r]);
        d2 = fmaxf(d2, 0.f);
        float d = __builtin_amdgcn_sqrtf(d2);
        if (DIAG) {
            if (jloc + r == il) d = 0.f;  // exact diagonal (ref: where(d2>0,...))
        }
        const float z = fmaf(d, c1, c0);
        p[r] = __builtin_amdgcn_rcpf(1.f + __builtin_amdgcn_exp2f(z));
    }
    u32 w0, w1;
    asm("v_cvt_pk_bf16_f32 %0, %1, %2" : "=v"(w0) : "v"(p[0]), "v"(p[1]));
    asm("v_cvt_pk_bf16_f32 %0, %1, %2" : "=v"(w1) : "v"(p[2]), "v"(p[3]));
    u32x2 pk = {w0, w1};
    *(u32x2*)(astr + awoff) = pk;
}

// ---------------- fused aggregation: 8-wave blocks, double-buffer, ONE barrier/jt ----------------
// (R17-exact structure; the two per-jt A-frag stores are PAIRED at h==1 so the byte-adjacent
// 16B writes issue back-to-back and coalesce into one 32B/lane L2 transaction)
template <bool STOREA>
__global__ void __launch_bounds__(512) k_agg(const u16* __restrict__ hhi, const u16* __restrict__ hlo,
                                             const float* __restrict__ sqv, const u16* __restrict__ Bt,
                                             float* __restrict__ P, u16* __restrict__ Afr,
                                             const float* __restrict__ tp, const float* __restrict__ thp) {
    // LDS = 2x4096 (hi) + 2x4096 (lo) + 8x2048 (a-strips) = 32768 B
    __shared__ __align__(16) char smem[32768];
    char* const bufh = smem;            // 2 x [64][32] bf16 hi (swizzled)
    char* const bufl = smem + 8192;     // 2 x [64][32] bf16 lo
    char* const astr0 = smem + 16384;   // 8 x [16][64] bf16 wave-private a-strips

    const int tid = threadIdx.x, lane = tid & 63, w = tid >> 6;  // w in [0,8)
    const int frow = lane & 15, fg = lane >> 4;
    const int dstbase = blockIdx.x * 128;
    const int chunk = blockIdx.y;
    const float t = tp[0], th = thp[0];
    const float c1 = -t * 1.44269504088896340736f;  // -t*log2(e)
    const float c0 = c1 * th;
    char* const astr = astr0 + w * 2048;
    const int dfi = blockIdx.x * 8 + w;  // global dst-fragment index [0,512)

    const bool stager = (tid < 256);
    const int srow = (tid & 255) >> 2, sc = tid & 3;
    const int swa = swzA(srow, sc);

    // dst (B-operand) frags + |h_i|^2, straight from global (L2-resident)
    const int igf = dstbase + w * 16 + frow;
    const short8 hdh = *(const short8*)(hhi + igf * 32 + fg * 8);
    const short8 hdl = *(const short8*)(hlo + igf * 32 + fg * 8);
    const float sq_i = sqv[igf];
    // diagonal: wave w's dst rows live in src-tile dstbase + (w>>2)*64, local row il
    const int jdiag = dstbase + ((w >> 2) << 6);
    const int il = (w & 3) * 16 + frow;

    int awo[4], ard[2];
#pragma unroll
    for (int jj = 0; jj < 4; jj++)
        awo[jj] = frow * 128 + (((2 * jj + (fg >> 1)) ^ (frow & 7)) << 4) + ((fg & 1) << 3);
#pragma unroll
    for (int h = 0; h < 2; h++) ard[h] = frow * 128 + (((4 * h + fg) ^ (frow & 7)) << 4);

    f32x4 outacc = {0.f, 0.f, 0.f, 0.f};
    const u16* bgp = Bt + frow * 8192;

    const int jt0 = chunk * NJT;
    // prologue: tile0 -> buf0 (via regs), tile1 -> regs (staging threads only)
    short8 pvh, pvl;
    if (stager) {
        pvh = *(const short8*)(hhi + ((jt0 * 64) + srow) * 32 + sc * 8);
        pvl = *(const short8*)(hlo + ((jt0 * 64) + srow) * 32 + sc * 8);
        *(short8*)(bufh + swa) = pvh;
        *(short8*)(bufl + swa) = pvl;
        if (NJT > 1) {
            const int jn = (jt0 + 1) * 64;
            pvh = *(const short8*)(hhi + (jn + srow) * 32 + sc * 8);
            pvl = *(const short8*)(hlo + (jn + srow) * 32 + sc * 8);
        }
    }

    short8 pAf0;  // h==0 A-frag held for the paired store at h==1
    for (int it = 0; it < NJT; ++it) {
        const int b = it & 1;
        const int jbase = (jt0 + it) * 64;
        // global loads for THIS tile, issued before the barrier so their latency hides
        // under barrier + staging + hs-reads + S'-MFMAs (fences below would otherwise pin them)
        f32x4 sqg[4];
        short8 bfg[2];
#pragma unroll
        for (int q = 0; q < 4; q++) sqg[q] = *(const f32x4*)(sqv + jbase + q * 16 + fg * 4);
#pragma unroll
        for (int q = 0; q < 2; q++) bfg[q] = *(const short8*)(bgp + jbase + q * 32 + fg * 8);
        // Single barrier: publishes tile `it` (stored last iter / prologue) AND separates
        // iter it-1's reads of buf[b^1] from this iter's write to buf[b^1].
        __syncthreads();
        if (stager) {
            if (it + 1 < NJT) {  // store tile it+1 (in regs) into the other buffer
                *(short8*)(bufh + (b ^ 1) * 4096 + swa) = pvh;
                *(short8*)(bufl + (b ^ 1) * 4096 + swa) = pvl;
            }
            if (it + 2 < NJT) {  // prefetch tile it+2 into regs
                const int jn = (jt0 + it + 2) * 64;
                pvh = *(const short8*)(hhi + (jn + srow) * 32 + sc * 8);
                pvl = *(const short8*)(hlo + (jn + srow) * 32 + sc * 8);
            }
        }
        char* const bh = bufh + b * 4096;
        char* const bl = bufl + b * 4096;
        const bool diag = (jbase == jdiag);
#pragma unroll
        for (int h = 0; h < 2; ++h) {
            const short8 hs0h = *(const short8*)(bh + swzA(h * 32 + frow, fg));
            const short8 hs0l = *(const short8*)(bl + swzA(h * 32 + frow, fg));
            const short8 hs1h = *(const short8*)(bh + swzA(h * 32 + 16 + frow, fg));
            const short8 hs1l = *(const short8*)(bl + swzA(h * 32 + 16 + frow, fg));
            // S' = Hs . Hd^T (swapped: acc->PV-A-frag transpose is a packed b64 LDS write)
            f32x4 s0 = {0.f, 0.f, 0.f, 0.f}, s1 = {0.f, 0.f, 0.f, 0.f};
            s0 = MFMA16(hs0h, hdh, s0, 0, 0, 0);
            s0 = MFMA16(hs0h, hdl, s0, 0, 0, 0);
            s0 = MFMA16(hs0l, hdh, s0, 0, 0, 0);
            s1 = MFMA16(hs1h, hdh, s1, 0, 0, 0);
            s1 = MFMA16(hs1h, hdl, s1, 0, 0, 0);
            s1 = MFMA16(hs1l, hdh, s1, 0, 0, 0);
            lds_order_fence();  // WAR: prior af read (prev h / prev jt) before these writes
            if (diag) {  // uniform branch: only 1 tile per wave-row-block has the diagonal
                ew_pack<true>(astr, awo[2 * h], s0, sqg[2 * h], sq_i, c0, c1, (2 * h) * 16 + fg * 4, il);
                ew_pack<true>(astr, awo[2 * h + 1], s1, sqg[2 * h + 1], sq_i, c0, c1, (2 * h + 1) * 16 + fg * 4, il);
            } else {
                ew_pack<false>(astr, awo[2 * h], s0, sqg[2 * h], sq_i, c0, c1, 0, -1);
                ew_pack<false>(astr, awo[2 * h + 1], s1, sqg[2 * h + 1], sq_i, c0, c1, 0, -1);
            }
            lds_order_fence();  // RAW: pack writes ordered before the af read (TBAA fix)
            // PV: out += a(16x32) @ B(32x16)
            const short8 af = *(const short8*)(astr + ard[h]);
            if (STOREA) {  // paired store: both 16B halves issue back-to-back at h==1
                if (h == 0) {
                    pAf0 = af;
                } else {
                    u16* ap = Afr + (dfi * 128 + (jt0 + it)) * 1024 + lane * 16;
                    *(short8*)(ap) = pAf0;
                    *(short8*)(ap + 8) = af;
                }
            }
            outacc = MFMA16(af, bfg[h], outacc, 0, 0, 0);
        }
    }
#pragma unroll
    for (int r = 0; r < 4; r++) {
        const int ig = dstbase + w * 16 + fg * 4 + r;
        P[(chunk * 8192 + ig) * 16 + frow] = outacc[r];
    }
}

// ---------------- pass-2 aggregation from materialized A: pure PV ----------------
__global__ void __launch_bounds__(512) k_agg2(const u16* __restrict__ Afr, const u16* __restrict__ Bt,
                                              float* __restrict__ P) {
    const int tid = threadIdx.x, lane = tid & 63, w = tid >> 6;
    const int frow = lane & 15, fg = lane >> 4;
    const int dstbase = blockIdx.x * 128;
    const int chunk = blockIdx.y;
    const int dfi = blockIdx.x * 8 + w;
    const u16* bgp = Bt + frow * 8192;
    const int jt0 = chunk * NJT;

    f32x4 outacc = {0.f, 0.f, 0.f, 0.f};
#pragma unroll
    for (int it = 0; it < NJT; ++it) {
        const int sti = jt0 + it;
        const int jbase = sti * 64;
        const u16* ap = Afr + (dfi * 128 + sti) * 1024 + lane * 16;
        const short8 af0 = *(const short8*)(ap);
        const short8 af1 = *(const short8*)(ap + 8);
        const short8 bf0 = *(const short8*)(bgp + jbase + fg * 8);
        const short8 bf1 = *(const short8*)(bgp + jbase + 32 + fg * 8);
        outacc = MFMA16(af0, bf0, outacc, 0, 0, 0);
        outacc = MFMA16(af1, bf1, outacc, 0, 0, 0);
    }
#pragma unroll
    for (int r = 0; r < 4; r++) {
        const int ig = dstbase + w * 16 + fg * 4 + r;
        P[(chunk * 8192 + ig) * 16 + frow] = outacc[r];
    }
}

// ---------------- reduce partials -> g1 -> B2t = (g1@gw2)^T / N (rows 8..15 zero) ----------------
__global__ void __launch_bounds__(256) k_reduce1(const float* __restrict__ P,
                                                 const float* __restrict__ gw2,
                                                 const float* __restrict__ gb1,
                                                 u16* __restrict__ B2t) {
    __shared__ float gs[128];
    const int tid = threadIdx.x;
    if (tid < 128) gs[tid] = gw2[tid];
    __syncthreads();
    const int j = blockIdx.x * 256 + tid;
    float g[16];
#pragma unroll
    for (int q = 0; q < 4; q++) {
        f32x4 v = *(const f32x4*)(P + j * 16 + q * 4);
        g[q * 4 + 0] = v[0]; g[q * 4 + 1] = v[1]; g[q * 4 + 2] = v[2]; g[q * 4 + 3] = v[3];
    }
#pragma unroll
    for (int c = 1; c < NCH; c++) {
#pragma unroll
        for (int q = 0; q < 4; q++) {
            f32x4 v = *(const f32x4*)(P + (c * 8192 + j) * 16 + q * 4);
            g[q * 4 + 0] += v[0]; g[q * 4 + 1] += v[1]; g[q * 4 + 2] += v[2]; g[q * 4 + 3] += v[3];
        }
    }
#pragma unroll
    for (int f = 0; f < 16; f++) g[f] = fmaxf(g[f] + gb1[f], 0.f);
    const float inv = 0.0001220703125f;
#pragma unroll
    for (int f2 = 0; f2 < 8; f2++) {
        float a = 0.f;
#pragma unroll
        for (int k = 0; k < 16; k++) a = fmaf(g[k], gs[k * 8 + f2], a);
        B2t[f2 * 8192 + j] = f2bf(a * inv);
    }
#pragma unroll
    for (int f2 = 8; f2 < 16; f2++) B2t[f2 * 8192 + j] = 0;
}

// ---------------- final: g2 -> relu(g2@lw1+lb1) -> @lw2+lb2 ----------------
__global__ void __launch_bounds__(256) k_final(const float* __restrict__ P,
                                               const float* __restrict__ gb2,
                                               const float* __restrict__ lw1,
                                               const float* __restrict__ lb1,
                                               const float* __restrict__ lw2,
                                               const float* __restrict__ lb2,
                                               float* __restrict__ out) {
    __shared__ float s1[128], s2[256];
    const int tid = threadIdx.x;
    if (tid < 128) s1[tid] = lw1[tid];
    s2[tid] = lw2[tid];
    __syncthreads();
    const int j = blockIdx.x * 256 + tid;
    float g[8];
#pragma unroll
    for (int q = 0; q < 2; q++) {
        f32x4 v = *(const f32x4*)(P + j * 16 + q * 4);
        g[q * 4 + 0] = v[0]; g[q * 4 + 1] = v[1]; g[q * 4 + 2] = v[2]; g[q * 4 + 3] = v[3];
    }
#pragma unroll
    for (int c = 1; c < NCH; c++) {
#pragma unroll
        for (int q = 0; q < 2; q++) {
            f32x4 v = *(const f32x4*)(P + (c * 8192 + j) * 16 + q * 4);
            g[q * 4 + 0] += v[0]; g[q * 4 + 1] += v[1]; g[q * 4 + 2] += v[2]; g[q * 4 + 3] += v[3];
        }
    }
#pragma unroll
    for (int f = 0; f < 8; f++) g[f] = fmaxf(g[f] + gb2[f], 0.f);
    float l1[16];
#pragma unroll
    for (int f = 0; f < 16; f++) {
        float a = lb1[f];
#pragma unroll
        for (int k = 0; k < 8; k++) a = fmaf(g[k], s1[k * 16 + f], a);
        l1[f] = fmaxf(a, 0.f);
    }
#pragma unroll
    for (int q = 0; q < 4; q++) {
        f32x4 v;
#pragma unroll
        for (int e = 0; e < 4; e++) {
            const int f = q * 4 + e;
            float a = lb2[f];
#pragma unroll
            for (int k = 0; k < 16; k++) a = fmaf(l1[k], s2[k * 16 + f], a);
            v[e] = a;
        }
        *(f32x4*)(out + j * 16 + q * 4) = v;
    }
}

extern "C" void kernel_launch(void* const* d_in, const int* in_sizes, int n_in,
                              void* d_out, int out_size, void* d_ws, size_t ws_size,
                              hipStream_t stream) {
    (void)in_sizes; (void)n_in; (void)out_size;
    const float* x   = (const float*)d_in[0];
    const float* w1  = (const float*)d_in[1];
    const float* b1  = (const float*)d_in[2];
    const float* w2  = (const float*)d_in[3];
    const float* b2  = (const float*)d_in[4];
    const float* w3  = (const float*)d_in[5];
    const float* b3  = (const float*)d_in[6];
    const float* t   = (const float*)d_in[7];
    const float* th  = (const float*)d_in[8];
    const float* gw1 = (const float*)d_in[9];
    const float* gb1 = (const float*)d_in[10];
    const float* gw2 = (const float*)d_in[11];
    const float* gb2 = (const float*)d_in[12];
    const float* lw1 = (const float*)d_in[13];
    const float* lb1 = (const float*)d_in[14];
    const float* lw2 = (const float*)d_in[15];
    const float* lb2 = (const float*)d_in[16];

    char* ws = (char*)d_ws;
    u16* wt1h = (u16*)(ws + 0);          // [256][512] hi
    u16* wt1l = (u16*)(ws + 262144);     // [256][512] lo
    u16* wt2h = (u16*)(ws + 524288);     // [256][256] hi
    u16* wt2l = (u16*)(ws + 655360);     // [256][256] lo
    u16* wt3h = (u16*)(ws + 786432);     // [32][256] hi
    u16* wt3l = (u16*)(ws + 802816);     // [32][256] lo
    u16* H1h  = (u16*)(ws + 819200);     // [8192][256] hi (aliased by P later)
    u16* H1l  = (u16*)(ws + 5013504);    // [8192][256] lo
    float* P  = (float*)(ws + 819200);   // [16][8192][16] partials (8MB, H1 dead by then)
    u16* H2h  = (u16*)(ws + 9207808);    // [8192][256] hi
    u16* H2l  = (u16*)(ws + 13402112);   // [8192][256] lo
    float* H  = (float*)(ws + 17596416); // [8192][32] f32
    u16*   hhi = (u16*)(ws + 18644992);  // [8192][32] bf16 hi
    u16*   hlo = (u16*)(ws + 19169280);  // [8192][32] bf16 lo
    float* sqv = (float*)(ws + 19693568);// [8192]
    u16*   B1t = (u16*)(ws + 19726336);  // [16][8192] bf16
    u16*   B2t = (u16*)(ws + 19988480);  // [16][8192] bf16 (rows 8..15 zero)
    u16*   Afr = (u16*)(ws + 20971520);  // [512 dfrag][128 stile][1024] bf16 = 134.2 MB
    const bool bigws = ws_size >= (20971520ull + 134217728ull);

    k_trs_all<<<800, 256, 0, stream>>>(w1, wt1h, wt1l, w2, wt2h, wt2l, w3, wt3h, wt3l);

    k_gemm<512, 64, true, true, true><<<dim3(128, 4), 256, 0, stream>>>(
        x, nullptr, nullptr, wt1h, wt1l, b1, nullptr, H1h, H1l, 256);
    k_gemm<256, 64, true, false, true><<<dim3(128, 4), 256, 0, stream>>>(
        nullptr, H1h, H1l, wt2h, wt2l, b2, nullptr, H2h, H2l, 256);
    k_gemm<256, 32, false, false, false><<<dim3(128, 1), 256, 0, stream>>>(
        nullptr, H2h, H2l, wt3h, wt3l, b3, H, nullptr, nullptr, 32);

    k_post<<<32, 256, 0, stream>>>(H, gw1, hhi, hlo, sqv, B1t);

    if (bigws) {
        k_agg<true><<<dim3(64, NCH), 512, 0, stream>>>(hhi, hlo, sqv, B1t, P, Afr, t, th);
        k_reduce1<<<32, 256, 0, stream>>>(P, gw2, gb1, B2t);
        k_agg2<<<dim3(64, NCH), 512, 0, stream>>>(Afr, B2t, P);
    } else {
        k_agg<false><<<dim3(64, NCH), 512, 0, stream>>>(hhi, hlo, sqv, B1t, P, nullptr, t, th);
        k_reduce1<<<32, 256, 0, stream>>>(P, gw2, gb1, B2t);
        k_agg<false><<<dim3(64, NCH), 512, 0, stream>>>(hhi, hlo, sqv, B2t, P, nullptr, t, th);
    }
    k_final<<<32, 256, 0, stream>>>(P, gb2, lw1, lb1, lw2, lb2, (float*)d_out);
}

// Round 21
// 121.310 us; speedup vs baseline: 1.4042x; 1.0240x over previous
//
#include <hip/hip_runtime.h>

typedef __attribute__((ext_vector_type(8))) short short8;
typedef __attribute__((ext_vector_type(4))) float f32x4;
typedef __attribute__((ext_vector_type(2))) unsigned int u32x2;
typedef unsigned short u16;
typedef unsigned int u32;

#define MFMA16 __builtin_amdgcn_mfma_f32_16x16x32_bf16

constexpr int NCH = 16;               // j-chunks per k_agg dispatch
constexpr int NJT = 8192 / 64 / NCH;  // 8 j-tiles per block

// compiler-level ordering fence for LDS a-strip (emits no instructions)
__device__ __forceinline__ void lds_order_fence() { asm volatile("" ::: "memory"); }

// async global->LDS: 16B per lane, dest = wave-uniform lds base + lane*16
__device__ __forceinline__ void gload_lds16(const void* g, void* l) {
    __builtin_amdgcn_global_load_lds((const __attribute__((address_space(1))) void*)g,
                                     (__attribute__((address_space(3))) void*)l, 16, 0, 0);
}

__device__ __forceinline__ u16 f2bf(float f) {
    u32 u = __builtin_bit_cast(u32, f);
    return (u16)((u + 0x7FFFu + ((u >> 16) & 1u)) >> 16);
}

// truncation split: f ~= hi + lo with ~16-bit combined mantissa (2^-16 rel)
__device__ __forceinline__ void split2(float f, u16& hi, u16& lo) {
    u32 u = __builtin_bit_cast(u32, f);
    hi = (u16)(u >> 16);
    float hf = __builtin_bit_cast(float, u & 0xFFFF0000u);
    float r = f - hf;  // exact (Sterbenz)
    lo = (u16)(__builtin_bit_cast(u32, r) >> 16);
}

// swizzle for [rows][32 bf16 = 64B] tiles, 4x16B slots/row: 2-way (free) on frag reads
__device__ __forceinline__ int swzA(int row, int slot) {
    return row * 64 + ((slot ^ ((row >> 1) & 3)) << 4);
}

// ---------------- merged weight transpose+split: w[K][N] -> wt{hi,lo}[N][K] ----------------
__global__ void __launch_bounds__(256) k_trs_all(const float* __restrict__ w1, u16* __restrict__ wt1h,
                                                 u16* __restrict__ wt1l,
                                                 const float* __restrict__ w2, u16* __restrict__ wt2h,
                                                 u16* __restrict__ wt2l,
                                                 const float* __restrict__ w3, u16* __restrict__ wt3h,
                                                 u16* __restrict__ wt3l) {
    const int idx = blockIdx.x * 256 + threadIdx.x;
    float v;
    int off;
    u16 *ph, *pl;
    if (idx < 131072) {  // w1: 512x256
        const int k = idx >> 8, n = idx & 255;
        v = w1[idx];
        off = n * 512 + k;
        ph = wt1h; pl = wt1l;
    } else if (idx < 196608) {  // w2: 256x256
        const int i2 = idx - 131072;
        const int k = i2 >> 8, n = i2 & 255;
        v = w2[i2];
        off = n * 256 + k;
        ph = wt2h; pl = wt2l;
    } else {  // w3: 256x32
        const int i3 = idx - 196608;
        const int k = i3 >> 5, n = i3 & 31;
        v = w3[i3];
        off = n * 256 + k;
        ph = wt3h; pl = wt3l;
    }
    u16 hh, ll;
    split2(v, hh, ll);
    ph[off] = hh;
    pl[off] = ll;
}

// ---------------- split-bf16 MFMA GEMM (BM=64) with global_load_lds staging ----------------
template <int K, int BN, bool RELU, bool AF32, bool OUTSPLIT>
__global__ void __launch_bounds__(256, 2) k_gemm(const float* __restrict__ Af,
                                                 const u16* __restrict__ Ahi,
                                                 const u16* __restrict__ Alo,
                                                 const u16* __restrict__ Bthi,
                                                 const u16* __restrict__ Btlo,
                                                 const float* __restrict__ bias,
                                                 float* __restrict__ Cf, u16* __restrict__ Chi,
                                                 u16* __restrict__ Clo, const int N) {
    constexpr int NT = BN / 16;
    __shared__ __align__(16) char smem[16384];
    char* const Ah = smem;
    char* const Al = smem + 4096;
    char* const Bh = smem + 8192;
    char* const Bl = smem + 12288;
    const int tid = threadIdx.x, lane = tid & 63, w = tid >> 6;
    const int frow = lane & 15, fg = lane >> 4;
    const int m0 = blockIdx.x * 64, n0 = blockIdx.y * BN;
    const int srow = tid >> 2, sc = tid & 3;
    const int swa = swzA(srow, sc);
    // pre-swizzled source addressing for global_load_lds (linear LDS dest tid*16)
    const int slot_ld = (tid & 3) ^ ((srow >> 1) & 3);
    const float* gA = AF32 ? (Af + (m0 + srow) * K + sc * 8) : nullptr;
    const u16* sAh = AF32 ? nullptr : (Ahi + (m0 + srow) * K + slot_ld * 8);
    const u16* sAl = AF32 ? nullptr : (Alo + (m0 + srow) * K + slot_ld * 8);
    const u16* sBh = Bthi + (n0 + srow) * K + slot_ld * 8;
    const u16* sBl = Btlo + (n0 + srow) * K + slot_ld * 8;
    char* const ldsAh = Ah + w * 1024;  // wave-uniform LDS bases
    char* const ldsAl = Al + w * 1024;
    char* const ldsBh = Bh + w * 1024;
    char* const ldsBl = Bl + w * 1024;

    f32x4 acc[NT];
    float bv[NT];
#pragma unroll
    for (int nt = 0; nt < NT; nt++) {
        acc[nt] = {0.f, 0.f, 0.f, 0.f};
        bv[nt] = bias[n0 + nt * 16 + frow];
    }
    const int fra = swzA(w * 16 + frow, fg);
    int frb[NT];
#pragma unroll
    for (int nt = 0; nt < NT; nt++) frb[nt] = swzA(nt * 16 + frow, fg);

    for (int k0 = 0; k0 < K; k0 += 32) {
        short8 ah8, al8;
        if constexpr (AF32) {  // f32 A: load+split in regs before the barrier (prefetch slack)
            const f32x4 a0 = *(const f32x4*)(gA + k0);
            const f32x4 a1 = *(const f32x4*)(gA + k0 + 4);
#pragma unroll
            for (int i = 0; i < 4; i++) { u16 hh, ll; split2(a0[i], hh, ll); ah8[i] = (short)hh; al8[i] = (short)ll; }
#pragma unroll
            for (int i = 0; i < 4; i++) { u16 hh, ll; split2(a1[i], hh, ll); ah8[4 + i] = (short)hh; al8[4 + i] = (short)ll; }
        }
        __syncthreads();  // previous iteration's frag reads done before overwrite
        if constexpr (AF32) {
            *(short8*)(Ah + swa) = ah8;
            *(short8*)(Al + swa) = al8;
        } else {
            gload_lds16(sAh + k0, ldsAh);
            gload_lds16(sAl + k0, ldsAl);
        }
        if (BN == 64) {  // all 4 waves cover the 64-row B tile
            gload_lds16(sBh + k0, ldsBh);
            gload_lds16(sBl + k0, ldsBl);
        } else if (w < 2) {  // BN=32: waves 0,1 cover 32 rows
            gload_lds16(sBh + k0, ldsBh);
            gload_lds16(sBl + k0, ldsBl);
        }
        __syncthreads();  // drains vmcnt(0): gload_lds data visible
        const short8 afh = *(const short8*)(Ah + fra);
        const short8 afl = *(const short8*)(Al + fra);
#pragma unroll
        for (int nt = 0; nt < NT; nt++) {
            const short8 bfh = *(const short8*)(Bh + frb[nt]);
            const short8 bfl = *(const short8*)(Bl + frb[nt]);
            acc[nt] = MFMA16(afh, bfh, acc[nt], 0, 0, 0);
            acc[nt] = MFMA16(afh, bfl, acc[nt], 0, 0, 0);
            acc[nt] = MFMA16(afl, bfh, acc[nt], 0, 0, 0);
        }
    }
#pragma unroll
    for (int nt = 0; nt < NT; nt++) {
#pragma unroll
        for (int r = 0; r < 4; r++) {
            float v = acc[nt][r] + bv[nt];
            if (RELU) v = fmaxf(v, 0.f);
            const int row = m0 + w * 16 + fg * 4 + r, col = n0 + nt * 16 + frow;
            if constexpr (OUTSPLIT) {
                u16 hh, ll;
                split2(v, hh, ll);
                Chi[row * N + col] = hh;
                Clo[row * N + col] = ll;
            } else {
                Cf[row * N + col] = v;
            }
        }
    }
}

// ---------------- post: sq, h hi/lo, B1t = (h@gw1)^T / N  (64 blocks x 128 thr) ----------------
__global__ void __launch_bounds__(128) k_post(const float* __restrict__ H,
                                              const float* __restrict__ gw1,
                                              u16* __restrict__ hhi, u16* __restrict__ hlo,
                                              float* __restrict__ sqv, u16* __restrict__ B1t) {
    __shared__ float gs[512];
    const int tid = threadIdx.x;
#pragma unroll
    for (int i = tid; i < 512; i += 128) gs[i] = gw1[i];
    __syncthreads();
    const int j = blockIdx.x * 128 + tid;
    float h[32];
#pragma unroll
    for (int q = 0; q < 8; q++) {
        f32x4 v = *(const f32x4*)(H + j * 32 + q * 4);
        h[q * 4 + 0] = v[0]; h[q * 4 + 1] = v[1]; h[q * 4 + 2] = v[2]; h[q * 4 + 3] = v[3];
    }
    float s = 0.f;
#pragma unroll
    for (int k = 0; k < 32; k++) s = fmaf(h[k], h[k], s);
    sqv[j] = s;
#pragma unroll
    for (int q = 0; q < 4; q++) {
        short8 vh, vl;
#pragma unroll
        for (int e = 0; e < 8; e++) {
            u16 hh, ll;
            split2(h[q * 8 + e], hh, ll);
            vh[e] = (short)hh; vl[e] = (short)ll;
        }
        *(short8*)(hhi + j * 32 + q * 8) = vh;
        *(short8*)(hlo + j * 32 + q * 8) = vl;
    }
    const float inv = 0.0001220703125f;  // 1/8192
#pragma unroll
    for (int f = 0; f < 16; f++) {
        float a = 0.f;
#pragma unroll
        for (int k = 0; k < 32; k++) a = fmaf(h[k], gs[k * 16 + f], a);
        B1t[f * 8192 + j] = f2bf(a * inv);
    }
}

// elementwise for one 16-src group: d2 -> d -> sigmoid -> bf16 pair-pack -> a-strip
template <bool DIAG>
__device__ __forceinline__ void ew_pack(char* astr, int awoff, const f32x4 s, const f32x4 sq4,
                                        float sq_i, float c0, float c1, int jloc, int il) {
    float p[4];
#pragma unroll
    for (int r = 0; r < 4; r++) {
        float d2 = fmaf(s[r], -2.f, sq_i + sq4[r]);
        d2 = fmaxf(d2, 0.f);
        float d = __builtin_amdgcn_sqrtf(d2);
        if (DIAG) {
            if (jloc + r == il) d = 0.f;  // exact diagonal (ref: where(d2>0,...))
        }
        const float z = fmaf(d, c1, c0);
        p[r] = __builtin_amdgcn_rcpf(1.f + __builtin_amdgcn_exp2f(z));
    }
    u32 w0, w1;
    asm("v_cvt_pk_bf16_f32 %0, %1, %2" : "=v"(w0) : "v"(p[0]), "v"(p[1]));
    asm("v_cvt_pk_bf16_f32 %0, %1, %2" : "=v"(w1) : "v"(p[2]), "v"(p[3]));
    u32x2 pk = {w0, w1};
    *(u32x2*)(astr + awoff) = pk;
}

// ---------------- fused aggregation: 8-wave blocks, double-buffer, ONE barrier/jt ----------------
// (R17-exact: proven best green at 124.0)
template <bool STOREA>
__global__ void __launch_bounds__(512) k_agg(const u16* __restrict__ hhi, const u16* __restrict__ hlo,
                                             const float* __restrict__ sqv, const u16* __restrict__ Bt,
                                             float* __restrict__ P, u16* __restrict__ Afr,
                                             const float* __restrict__ tp, const float* __restrict__ thp) {
    // LDS = 2x4096 (hi) + 2x4096 (lo) + 8x2048 (a-strips) = 32768 B
    __shared__ __align__(16) char smem[32768];
    char* const bufh = smem;            // 2 x [64][32] bf16 hi (swizzled)
    char* const bufl = smem + 8192;     // 2 x [64][32] bf16 lo
    char* const astr0 = smem + 16384;   // 8 x [16][64] bf16 wave-private a-strips

    const int tid = threadIdx.x, lane = tid & 63, w = tid >> 6;  // w in [0,8)
    const int frow = lane & 15, fg = lane >> 4;
    const int dstbase = blockIdx.x * 128;
    const int chunk = blockIdx.y;
    const float t = tp[0], th = thp[0];
    const float c1 = -t * 1.44269504088896340736f;  // -t*log2(e)
    const float c0 = c1 * th;
    char* const astr = astr0 + w * 2048;
    const int dfi = blockIdx.x * 8 + w;  // global dst-fragment index [0,512)

    const bool stager = (tid < 256);
    const int srow = (tid & 255) >> 2, sc = tid & 3;
    const int swa = swzA(srow, sc);

    // dst (B-operand) frags + |h_i|^2, straight from global (L2-resident)
    const int igf = dstbase + w * 16 + frow;
    const short8 hdh = *(const short8*)(hhi + igf * 32 + fg * 8);
    const short8 hdl = *(const short8*)(hlo + igf * 32 + fg * 8);
    const float sq_i = sqv[igf];
    // diagonal: wave w's dst rows live in src-tile dstbase + (w>>2)*64, local row il
    const int jdiag = dstbase + ((w >> 2) << 6);
    const int il = (w & 3) * 16 + frow;

    int awo[4], ard[2];
#pragma unroll
    for (int jj = 0; jj < 4; jj++)
        awo[jj] = frow * 128 + (((2 * jj + (fg >> 1)) ^ (frow & 7)) << 4) + ((fg & 1) << 3);
#pragma unroll
    for (int h = 0; h < 2; h++) ard[h] = frow * 128 + (((4 * h + fg) ^ (frow & 7)) << 4);

    f32x4 outacc = {0.f, 0.f, 0.f, 0.f};
    const u16* bgp = Bt + frow * 8192;

    const int jt0 = chunk * NJT;
    // prologue: tile0 -> buf0 (via regs), tile1 -> regs (staging threads only)
    short8 pvh, pvl;
    if (stager) {
        pvh = *(const short8*)(hhi + ((jt0 * 64) + srow) * 32 + sc * 8);
        pvl = *(const short8*)(hlo + ((jt0 * 64) + srow) * 32 + sc * 8);
        *(short8*)(bufh + swa) = pvh;
        *(short8*)(bufl + swa) = pvl;
        if (NJT > 1) {
            const int jn = (jt0 + 1) * 64;
            pvh = *(const short8*)(hhi + (jn + srow) * 32 + sc * 8);
            pvl = *(const short8*)(hlo + (jn + srow) * 32 + sc * 8);
        }
    }

    for (int it = 0; it < NJT; ++it) {
        const int b = it & 1;
        const int jbase = (jt0 + it) * 64;
        // global loads for THIS tile, issued before the barrier so their latency hides
        // under barrier + staging + hs-reads + S'-MFMAs (fences below would otherwise pin them)
        f32x4 sqg[4];
        short8 bfg[2];
#pragma unroll
        for (int q = 0; q < 4; q++) sqg[q] = *(const f32x4*)(sqv + jbase + q * 16 + fg * 4);
#pragma unroll
        for (int q = 0; q < 2; q++) bfg[q] = *(const short8*)(bgp + jbase + q * 32 + fg * 8);
        // Single barrier: publishes tile `it` (stored last iter / prologue) AND separates
        // iter it-1's reads of buf[b^1] from this iter's write to buf[b^1].
        __syncthreads();
        if (stager) {
            if (it + 1 < NJT) {  // store tile it+1 (in regs) into the other buffer
                *(short8*)(bufh + (b ^ 1) * 4096 + swa) = pvh;
                *(short8*)(bufl + (b ^ 1) * 4096 + swa) = pvl;
            }
            if (it + 2 < NJT) {  // prefetch tile it+2 into regs
                const int jn = (jt0 + it + 2) * 64;
                pvh = *(const short8*)(hhi + (jn + srow) * 32 + sc * 8);
                pvl = *(const short8*)(hlo + (jn + srow) * 32 + sc * 8);
            }
        }
        char* const bh = bufh + b * 4096;
        char* const bl = bufl + b * 4096;
        const bool diag = (jbase == jdiag);
#pragma unroll
        for (int h = 0; h < 2; ++h) {
            const short8 hs0h = *(const short8*)(bh + swzA(h * 32 + frow, fg));
            const short8 hs0l = *(const short8*)(bl + swzA(h * 32 + frow, fg));
            const short8 hs1h = *(const short8*)(bh + swzA(h * 32 + 16 + frow, fg));
            const short8 hs1l = *(const short8*)(bl + swzA(h * 32 + 16 + frow, fg));
            // S' = Hs . Hd^T (swapped: acc->PV-A-frag transpose is a packed b64 LDS write)
            f32x4 s0 = {0.f, 0.f, 0.f, 0.f}, s1 = {0.f, 0.f, 0.f, 0.f};
            s0 = MFMA16(hs0h, hdh, s0, 0, 0, 0);
            s0 = MFMA16(hs0h, hdl, s0, 0, 0, 0);
            s0 = MFMA16(hs0l, hdh, s0, 0, 0, 0);
            s1 = MFMA16(hs1h, hdh, s1, 0, 0, 0);
            s1 = MFMA16(hs1h, hdl, s1, 0, 0, 0);
            s1 = MFMA16(hs1l, hdh, s1, 0, 0, 0);
            lds_order_fence();  // WAR: prior af read (prev h / prev jt) before these writes
            if (diag) {  // uniform branch: only 1 tile per wave-row-block has the diagonal
                ew_pack<true>(astr, awo[2 * h], s0, sqg[2 * h], sq_i, c0, c1, (2 * h) * 16 + fg * 4, il);
                ew_pack<true>(astr, awo[2 * h + 1], s1, sqg[2 * h + 1], sq_i, c0, c1, (2 * h + 1) * 16 + fg * 4, il);
            } else {
                ew_pack<false>(astr, awo[2 * h], s0, sqg[2 * h], sq_i, c0, c1, 0, -1);
                ew_pack<false>(astr, awo[2 * h + 1], s1, sqg[2 * h + 1], sq_i, c0, c1, 0, -1);
            }
            lds_order_fence();  // RAW: pack writes ordered before the af read (TBAA fix)
            // PV: out += a(16x32) @ B(32x16)
            const short8 af = *(const short8*)(astr + ard[h]);
            if (STOREA) {  // materialize A-fragment (data-dep on af keeps order)
                *(short8*)(Afr + (dfi * 128 + (jt0 + it)) * 1024 + lane * 16 + h * 8) = af;
            }
            outacc = MFMA16(af, bfg[h], outacc, 0, 0, 0);
        }
    }
#pragma unroll
    for (int r = 0; r < 4; r++) {
        const int ig = dstbase + w * 16 + fg * 4 + r;
        P[(chunk * 8192 + ig) * 16 + frow] = outacc[r];
    }
}

// ---------------- pass-2 aggregation from materialized A: pure PV ----------------
__global__ void __launch_bounds__(512) k_agg2(const u16* __restrict__ Afr, const u16* __restrict__ Bt,
                                              float* __restrict__ P) {
    const int tid = threadIdx.x, lane = tid & 63, w = tid >> 6;
    const int frow = lane & 15, fg = lane >> 4;
    const int dstbase = blockIdx.x * 128;
    const int chunk = blockIdx.y;
    const int dfi = blockIdx.x * 8 + w;
    const u16* bgp = Bt + frow * 8192;
    const int jt0 = chunk * NJT;

    f32x4 outacc = {0.f, 0.f, 0.f, 0.f};
#pragma unroll
    for (int it = 0; it < NJT; ++it) {
        const int sti = jt0 + it;
        const int jbase = sti * 64;
        const u16* ap = Afr + (dfi * 128 + sti) * 1024 + lane * 16;
        const short8 af0 = *(const short8*)(ap);
        const short8 af1 = *(const short8*)(ap + 8);
        const short8 bf0 = *(const short8*)(bgp + jbase + fg * 8);
        const short8 bf1 = *(const short8*)(bgp + jbase + 32 + fg * 8);
        outacc = MFMA16(af0, bf0, outacc, 0, 0, 0);
        outacc = MFMA16(af1, bf1, outacc, 0, 0, 0);
    }
#pragma unroll
    for (int r = 0; r < 4; r++) {
        const int ig = dstbase + w * 16 + fg * 4 + r;
        P[(chunk * 8192 + ig) * 16 + frow] = outacc[r];
    }
}

// ---------------- reduce partials -> g1 -> B2t (128 blocks x 64 thr) ----------------
__global__ void __launch_bounds__(64) k_reduce1(const float* __restrict__ P,
                                                const float* __restrict__ gw2,
                                                const float* __restrict__ gb1,
                                                u16* __restrict__ B2t) {
    __shared__ float gs[128];
    const int tid = threadIdx.x;
#pragma unroll
    for (int i = tid; i < 128; i += 64) gs[i] = gw2[i];
    __syncthreads();
    const int j = blockIdx.x * 64 + tid;
    float g[16];
#pragma unroll
    for (int q = 0; q < 4; q++) {
        f32x4 v = *(const f32x4*)(P + j * 16 + q * 4);
        g[q * 4 + 0] = v[0]; g[q * 4 + 1] = v[1]; g[q * 4 + 2] = v[2]; g[q * 4 + 3] = v[3];
    }
#pragma unroll
    for (int c = 1; c < NCH; c++) {
#pragma unroll
        for (int q = 0; q < 4; q++) {
            f32x4 v = *(const f32x4*)(P + (c * 8192 + j) * 16 + q * 4);
            g[q * 4 + 0] += v[0]; g[q * 4 + 1] += v[1]; g[q * 4 + 2] += v[2]; g[q * 4 + 3] += v[3];
        }
    }
#pragma unroll
    for (int f = 0; f < 16; f++) g[f] = fmaxf(g[f] + gb1[f], 0.f);
    const float inv = 0.0001220703125f;
#pragma unroll
    for (int f2 = 0; f2 < 8; f2++) {
        float a = 0.f;
#pragma unroll
        for (int k = 0; k < 16; k++) a = fmaf(g[k], gs[k * 8 + f2], a);
        B2t[f2 * 8192 + j] = f2bf(a * inv);
    }
#pragma unroll
    for (int f2 = 8; f2 < 16; f2++) B2t[f2 * 8192 + j] = 0;
}

// ---------------- final: g2 -> relu(g2@lw1+lb1) -> @lw2+lb2 (128 blocks x 64 thr) ----------------
__global__ void __launch_bounds__(64) k_final(const float* __restrict__ P,
                                              const float* __restrict__ gb2,
                                              const float* __restrict__ lw1,
                                              const float* __restrict__ lb1,
                                              const float* __restrict__ lw2,
                                              const float* __restrict__ lb2,
                                              float* __restrict__ out) {
    __shared__ float s1[128], s2[256];
    const int tid = threadIdx.x;
#pragma unroll
    for (int i = tid; i < 128; i += 64) s1[i] = lw1[i];
#pragma unroll
    for (int i = tid; i < 256; i += 64) s2[i] = lw2[i];
    __syncthreads();
    const int j = blockIdx.x * 64 + tid;
    float g[8];
#pragma unroll
    for (int q = 0; q < 2; q++) {
        f32x4 v = *(const f32x4*)(P + j * 16 + q * 4);
        g[q * 4 + 0] = v[0]; g[q * 4 + 1] = v[1]; g[q * 4 + 2] = v[2]; g[q * 4 + 3] = v[3];
    }
#pragma unroll
    for (int c = 1; c < NCH; c++) {
#pragma unroll
        for (int q = 0; q < 2; q++) {
            f32x4 v = *(const f32x4*)(P + (c * 8192 + j) * 16 + q * 4);
            g[q * 4 + 0] += v[0]; g[q * 4 + 1] += v[1]; g[q * 4 + 2] += v[2]; g[q * 4 + 3] += v[3];
        }
    }
#pragma unroll
    for (int f = 0; f < 8; f++) g[f] = fmaxf(g[f] + gb2[f], 0.f);
    float l1[16];
#pragma unroll
    for (int f = 0; f < 16; f++) {
        float a = lb1[f];
#pragma unroll
        for (int k = 0; k < 8; k++) a = fmaf(g[k], s1[k * 16 + f], a);
        l1[f] = fmaxf(a, 0.f);
    }
#pragma unroll
    for (int q = 0; q < 4; q++) {
        f32x4 v;
#pragma unroll
        for (int e = 0; e < 4; e++) {
            const int f = q * 4 + e;
            float a = lb2[f];
#pragma unroll
            for (int k = 0; k < 16; k++) a = fmaf(l1[k], s2[k * 16 + f], a);
            v[e] = a;
        }
        *(f32x4*)(out + j * 16 + q * 4) = v;
    }
}

extern "C" void kernel_launch(void* const* d_in, const int* in_sizes, int n_in,
                              void* d_out, int out_size, void* d_ws, size_t ws_size,
                              hipStream_t stream) {
    (void)in_sizes; (void)n_in; (void)out_size;
    const float* x   = (const float*)d_in[0];
    const float* w1  = (const float*)d_in[1];
    const float* b1  = (const float*)d_in[2];
    const float* w2  = (const float*)d_in[3];
    const float* b2  = (const float*)d_in[4];
    const float* w3  = (const float*)d_in[5];
    const float* b3  = (const float*)d_in[6];
    const float* t   = (const float*)d_in[7];
    const float* th  = (const float*)d_in[8];
    const float* gw1 = (const float*)d_in[9];
    const float* gb1 = (const float*)d_in[10];
    const float* gw2 = (const float*)d_in[11];
    const float* gb2 = (const float*)d_in[12];
    const float* lw1 = (const float*)d_in[13];
    const float* lb1 = (const float*)d_in[14];
    const float* lw2 = (const float*)d_in[15];
    const float* lb2 = (const float*)d_in[16];

    char* ws = (char*)d_ws;
    u16* wt1h = (u16*)(ws + 0);          // [256][512] hi
    u16* wt1l = (u16*)(ws + 262144);     // [256][512] lo
    u16* wt2h = (u16*)(ws + 524288);     // [256][256] hi
    u16* wt2l = (u16*)(ws + 655360);     // [256][256] lo
    u16* wt3h = (u16*)(ws + 786432);     // [32][256] hi
    u16* wt3l = (u16*)(ws + 802816);     // [32][256] lo
    u16* H1h  = (u16*)(ws + 819200);     // [8192][256] hi (aliased by P later)
    u16* H1l  = (u16*)(ws + 5013504);    // [8192][256] lo
    float* P  = (float*)(ws + 819200);   // [16][8192][16] partials (8MB, H1 dead by then)
    u16* H2h  = (u16*)(ws + 9207808);    // [8192][256] hi
    u16* H2l  = (u16*)(ws + 13402112);   // [8192][256] lo
    float* H  = (float*)(ws + 17596416); // [8192][32] f32
    u16*   hhi = (u16*)(ws + 18644992);  // [8192][32] bf16 hi
    u16*   hlo = (u16*)(ws + 19169280);  // [8192][32] bf16 lo
    float* sqv = (float*)(ws + 19693568);// [8192]
    u16*   B1t = (u16*)(ws + 19726336);  // [16][8192] bf16
    u16*   B2t = (u16*)(ws + 19988480);  // [16][8192] bf16 (rows 8..15 zero)
    u16*   Afr = (u16*)(ws + 20971520);  // [512 dfrag][128 stile][1024] bf16 = 134.2 MB
    const bool bigws = ws_size >= (20971520ull + 134217728ull);

    k_trs_all<<<800, 256, 0, stream>>>(w1, wt1h, wt1l, w2, wt2h, wt2l, w3, wt3h, wt3l);

    k_gemm<512, 64, true, true, true><<<dim3(128, 4), 256, 0, stream>>>(
        x, nullptr, nullptr, wt1h, wt1l, b1, nullptr, H1h, H1l, 256);
    k_gemm<256, 64, true, false, true><<<dim3(128, 4), 256, 0, stream>>>(
        nullptr, H1h, H1l, wt2h, wt2l, b2, nullptr, H2h, H2l, 256);
    k_gemm<256, 32, false, false, false><<<dim3(128, 1), 256, 0, stream>>>(
        nullptr, H2h, H2l, wt3h, wt3l, b3, H, nullptr, nullptr, 32);

    k_post<<<64, 128, 0, stream>>>(H, gw1, hhi, hlo, sqv, B1t);

    if (bigws) {
        k_agg<true><<<dim3(64, NCH), 512, 0, stream>>>(hhi, hlo, sqv, B1t, P, Afr, t, th);
        k_reduce1<<<128, 64, 0, stream>>>(P, gw2, gb1, B2t);
        k_agg2<<<dim3(64, NCH), 512, 0, stream>>>(Afr, B2t, P);
    } else {
        k_agg<false><<<dim3(64, NCH), 512, 0, stream>>>(hhi, hlo, sqv, B1t, P, nullptr, t, th);
        k_reduce1<<<128, 64, 0, stream>>>(P, gw2, gb1, B2t);
        k_agg<false><<<dim3(64, NCH), 512, 0, stream>>>(hhi, hlo, sqv, B2t, P, nullptr, t, th);
    }
    k_final<<<128, 64, 0, stream>>>(P, gb2, lw1, lb1, lw2, lb2, (float*)d_out);
}